// Round 13
// baseline (100.827 us; speedup 1.0000x reference)
//
#include <hip/hip_runtime.h>
#include <hip/hip_bf16.h>

#define DIM 1024
#define STATE 256
#define BATCH 4
#define SEQ 4096
#define M_TOT (BATCH * SEQ)  // 16384

typedef short short8 __attribute__((ext_vector_type(8)));
typedef float f32x4 __attribute__((ext_vector_type(4)));

__device__ __forceinline__ unsigned short f2bf(float f) {
  unsigned int u = __float_as_uint(f);
  u += 0x7fff + ((u >> 16) & 1);  // RNE
  return (unsigned short)(u >> 16);
}

__device__ __forceinline__ float bf2f(unsigned short u) {
  return __uint_as_float((unsigned int)u << 16);
}

__device__ __forceinline__ void gl_lds16(const void* g, void* l) {
  __builtin_amdgcn_global_load_lds(
      (const __attribute__((address_space(1))) void*)g,
      (__attribute__((address_space(3))) void*)l, 16, 0, 0);
}

#define C2F 2.8853900817779268f   // 2*log2(e)
#define LOG2EF 1.4426950408889634f
#define VMC(N) asm volatile("s_waitcnt vmcnt(" #N ")" ::: "memory")

// ---------------- convert_bw: Bw -> bwb (bf16) only (r12, unchanged) ---------
__global__ __launch_bounds__(256) void convert_bw(
    const float* __restrict__ Bw, unsigned short* __restrict__ bwb) {
  const int r = blockIdx.x;
  const int c = threadIdx.x * 4;
  const float4 v = *(const float4*)(Bw + (size_t)r * DIM + c);
  *(ushort4*)(bwb + (size_t)r * DIM + c) =
      make_ushort4(f2bf(v.x), f2bf(v.y), f2bf(v.z), f2bf(v.w));
}

// ---------------- gemm_GX v4 (r10-proven, unchanged) -------------------------
__global__ __launch_bounds__(256, 2) void gemm_GX(
    const float* __restrict__ x,             // [16384][1024] f32
    const unsigned short* __restrict__ bwb,  // [256][1024] bf16
    const float* __restrict__ Bb,            // [256]
    const float* __restrict__ A,             // [256]
    unsigned short* __restrict__ G,          // [16384][256] bf16 (out)
    unsigned short* __restrict__ xb)         // [16384][1024] bf16 (out)
{
  __shared__ char lds[81920];  // 2 slots x 40960 (A 8KB @0, B 32KB @8192)

  const int tid = threadIdx.x;
  const int wave = tid >> 6;
  const int lane = tid & 63;
  const int lr = lane & 15;
  const int lk = lane >> 4;
  const int m0 = blockIdx.x * 32;

  f32x4 acc[2][4];
#pragma unroll
  for (int i = 0; i < 2; ++i)
#pragma unroll
    for (int j = 0; j < 4; ++j) acc[i][j] = (f32x4){0.f, 0.f, 0.f, 0.f};

  const char* xB  = (const char*)x;
  const char* bwB = (const char*)bwb;
  char* xbB = (char*)xb;

  auto stage = [&](int kt) {
    if (kt >= 16) return;
    char* slot = lds + (kt & 1) * 40960;
#pragma unroll
    for (int i = 0; i < 2; ++i) {   // A: [32 rows][256B f32], XOR(r&7)
      const int s = i * 256 + tid;
      const int r = s >> 4;
      const int c = (s & 15) ^ (r & 7);
      gl_lds16(xB + (size_t)(m0 + r) * 4096 + (size_t)kt * 256 + c * 16,
               slot + i * 4096 + wave * 1024);
    }
#pragma unroll
    for (int i = 0; i < 8; ++i) {   // B: [256 rows][128B bf16], XOR(r&7)
      const int s = i * 256 + tid;
      const int r = s >> 3;
      const int c = (s & 7) ^ (r & 7);
      gl_lds16(bwB + (size_t)r * 2048 + (size_t)kt * 128 + c * 16,
               slot + 8192 + i * 4096 + wave * 1024);
    }
  };

  stage(0);
  VMC(0);
  __builtin_amdgcn_s_barrier();
  stage(1);

  for (int t = 0; t < 16; ++t) {
    const char* As = lds + (t & 1) * 40960;
    const char* Bs = As + 8192;

    short8 af[2][2];  // [kk][f]
#pragma unroll
    for (int kk = 0; kk < 2; ++kk)
#pragma unroll
      for (int f = 0; f < 2; ++f) {
        const int row = f * 16 + lr;
        const int sw = row & 7;
        const f32x4 a0 = *(const f32x4*)(As + row * 256 + (((kk * 8 + 2 * lk)     ^ sw) << 4));
        const f32x4 a1 = *(const f32x4*)(As + row * 256 + (((kk * 8 + 2 * lk + 1) ^ sw) << 4));
        short8 v;
#pragma unroll
        for (int j = 0; j < 4; ++j) {
          v[j]     = (short)f2bf(a0[j]);
          v[4 + j] = (short)f2bf(a1[j]);
        }
        af[kk][f] = v;
      }
    short8 bfr[2][4];
#pragma unroll
    for (int kk = 0; kk < 2; ++kk)
#pragma unroll
      for (int fj = 0; fj < 4; ++fj) {
        const int n = wave * 64 + fj * 16 + lr;
        bfr[kk][fj] = *(const short8*)(Bs + n * 128 + (((kk * 4 + lk) ^ (n & 7)) << 4));
      }
#pragma unroll
    for (int kk = 0; kk < 2; ++kk)
#pragma unroll
      for (int f = 0; f < 2; ++f)
#pragma unroll
        for (int fj = 0; fj < 4; ++fj)
          acc[f][fj] = __builtin_amdgcn_mfma_f32_16x16x32_bf16(
              af[kk][f], bfr[kk][fj], acc[f][fj], 0, 0, 0);

    if ((t & 3) == wave) {
#pragma unroll
      for (int kk = 0; kk < 2; ++kk)
#pragma unroll
        for (int f = 0; f < 2; ++f) {
          const int row = f * 16 + lr;
          *(short8*)(xbB + (size_t)(m0 + row) * 2048 +
                     (size_t)t * 128 + kk * 64 + lk * 16) = af[kk][f];
        }
    }

    if (t < 15) {
      VMC(0);
      __builtin_amdgcn_s_barrier();
      stage(t + 2);
    }
  }

#pragma unroll
  for (int fj = 0; fj < 4; ++fj) {
    const int cg = wave * 64 + fj * 16 + lr;
    const float bbv = fmaf(Bb[cg], C2F,
                           C2F * __builtin_amdgcn_exp2f(A[cg] * LOG2EF));
#pragma unroll
    for (int f = 0; f < 2; ++f)
#pragma unroll
      for (int j = 0; j < 4; ++j) {
        const int rg = m0 + f * 16 + lk * 4 + j;
        G[(size_t)rg * STATE + cg] = f2bf(fmaf(acc[f][fj][j], C2F, bbv));
      }
  }
}

// ---------------- scan: wob conversion head + chunked scan (r12, unchanged) --
__global__ __launch_bounds__(256) void scan_kernel(
    const unsigned short* __restrict__ G,   // [16384][256] bf16
    const float* __restrict__ A,            // [256]
    const float* __restrict__ Cw,           // [1024][256] f32
    const float* __restrict__ Dw,           // [1024][1024] f32
    unsigned short* __restrict__ wob,       // [1024][1280] bf16 (out)
    unsigned short* __restrict__ states)    // [16384][256] bf16 (out)
{
  const int tid = threadIdx.x;
  const int e0 = blockIdx.x * 4;
#pragma unroll
  for (int rr = 0; rr < 4; ++rr) {
    const int e = e0 + rr;
    if (tid < 64) {
      const float4 v = *(const float4*)(Cw + (size_t)e * STATE + tid * 4);
      *(ushort4*)(wob + (size_t)e * 1280 + tid * 4) =
          make_ushort4(f2bf(v.x), f2bf(v.y), f2bf(v.z), f2bf(v.w));
    }
    const float4 v = *(const float4*)(Dw + (size_t)e * DIM + tid * 4);
    *(ushort4*)(wob + (size_t)e * 1280 + 256 + tid * 4) =
        make_ushort4(f2bf(v.x), f2bf(v.y), f2bf(v.z), f2bf(v.w));
  }

  const int b = blockIdx.x >> 6;
  const int chunk = blockIdx.x & 63;
  const int n = tid;
  const int t0 = chunk * 64;
  const int start = (t0 > 64) ? (t0 - 64) : 0;
  const int nw = t0 - start;
  const int total = nw + 64;

  const unsigned short* g = G + ((size_t)b * SEQ + start) * STATE + n;
  unsigned short* q = states + ((size_t)b * SEQ + start) * STATE + n;
  const float P = C2F * __builtin_amdgcn_exp2f(A[n] * LOG2EF);
  const float mP2 = -2.0f * P;

  float r = 0.5f;
  constexpr int CH = 16;
  float cur[CH], nxt[CH];
#pragma unroll
  for (int j = 0; j < CH; ++j) cur[j] = bf2f(g[(size_t)j * STATE]);

  const int NC = total / CH;
  for (int c = 0; c < NC; ++c) {
    if (c + 1 < NC) {
      const unsigned short* pn = g + (size_t)(c + 1) * CH * STATE;
#pragma unroll
      for (int j = 0; j < CH; ++j) nxt[j] = bf2f(pn[(size_t)j * STATE]);
    }
    if (c * CH >= nw) {
      unsigned short* qc = q + (size_t)c * CH * STATE;
#pragma unroll
      for (int j = 0; j < CH; ++j) {
        const float t = fmaf(mP2, r, cur[j]);
        const float e = __builtin_amdgcn_exp2f(t);
        r = __builtin_amdgcn_rcpf(1.0f + e);
        const float s = fmaf(-2.0f, r, 1.0f);
        qc[(size_t)j * STATE] = f2bf(s);
      }
    } else {
#pragma unroll
      for (int j = 0; j < CH; ++j) {
        const float t = fmaf(mP2, r, cur[j]);
        const float e = __builtin_amdgcn_exp2f(t);
        r = __builtin_amdgcn_rcpf(1.0f + e);
      }
    }
    if (c + 1 < NC) {
#pragma unroll
      for (int j = 0; j < CH; ++j) cur[j] = nxt[j];
    }
  }
}

// ---------------- gemm_out v3: 2-resident single-buffer (r10-GX pattern) -----
// dout = [states|x] @ [Cw|Dw]^T + Cb + Db. BM=128, BN=256, BK=64, K=1280
// (20 tiles). Grid 512 = 2 blocks/CU on all 256 CUs (the point: the
// co-resident block's compute hides this block's stage+VMC(0) drain -- the
// mechanism that took gemm_GX 35->22us in r10). LDS single slot 48KB
// (A 16KB @0, B 32KB @16384). 8 waves (2m x 4n), per-wave 64x64 out,
// acc[4][4] = 64 VGPR. Per tile: {per-kk frags + 16 MFMA (setprio)} x2 ->
// barrier -> stage(t+1) -> VMC(0) -> barrier. XOR(r&7) chunk swizzle
// (0-conflict, r4/r6-proven). Bijective 512-grid XCD swizzle.
__global__ __launch_bounds__(512, 4) void gemm_out(
    const unsigned short* __restrict__ stb,  // [16384][256] bf16
    const unsigned short* __restrict__ xb,   // [16384][1024] bf16
    const unsigned short* __restrict__ wob,  // [1024][1280] bf16
    const float* __restrict__ Cb,            // [1024]
    const float* __restrict__ Db,            // [1024]
    float* __restrict__ dout)                // [16384][1024] f32
{
  __shared__ char lds[49152];  // A 16KB @0, B 32KB @16384 (single slot)

  const int tid = threadIdx.x;
  const int wave = tid >> 6;
  const int lane = tid & 63;
  const int lr = lane & 15;
  const int lk = lane >> 4;
  const int wm = wave >> 2;  // 0..1 (m half)
  const int wn = wave & 3;   // 0..3 (n quarter)

  const int bs = ((blockIdx.x & 7) << 6) | (blockIdx.x >> 3);  // XCD swizzle (512%8==0)
  const int m0 = (bs >> 2) * 128;
  const int n0 = (bs & 3) * 256;

  const char* stbB = (const char*)stb;
  const char* xbB  = (const char*)xb;
  const char* wobB = (const char*)wob;

  f32x4 acc[4][4];
#pragma unroll
  for (int i = 0; i < 4; ++i)
#pragma unroll
    for (int j = 0; j < 4; ++j) acc[i][j] = (f32x4){0.f, 0.f, 0.f, 0.f};

  // stage K-tile kt: A 128x64 bf16 (2 loads/thr), B 256x64 bf16 (4 loads/thr)
  auto stage = [&](int kt) {
    if (kt >= 20) return;
    const char* abase;
    size_t astr, acolb;
    if (kt < 4) { abase = stbB; astr = 512;  acolb = (size_t)kt * 128; }
    else        { abase = xbB;  astr = 2048; acolb = (size_t)(kt - 4) * 128; }
    abase += (size_t)m0 * astr;
#pragma unroll
    for (int i2 = 0; i2 < 2; ++i2) {   // A: [128 rows][128B], 8 chunks, XOR(r&7)
      const int s = i2 * 512 + tid;
      const int r = s >> 3;
      const int cl = (s & 7) ^ (r & 7);
      gl_lds16(abase + (size_t)r * astr + acolb + cl * 16,
               lds + i2 * 8192 + wave * 1024);
    }
#pragma unroll
    for (int i2 = 0; i2 < 4; ++i2) {   // B: [256 rows][128B], 8 chunks, XOR(r&7)
      const int s = i2 * 512 + tid;
      const int r = s >> 3;
      const int cl = (s & 7) ^ (r & 7);
      gl_lds16(wobB + (size_t)(n0 + r) * 2560 + (size_t)kt * 128 + cl * 16,
               lds + 16384 + i2 * 8192 + wave * 1024);
    }
  };

  // prologue
  stage(0);
  VMC(0);
  __builtin_amdgcn_s_barrier();

  const char* As = lds;
  const char* Bs = lds + 16384;
  for (int t = 0; t < 20; ++t) {
#pragma unroll
    for (int kk = 0; kk < 2; ++kk) {
      short8 af[4], bfr[4];
#pragma unroll
      for (int fi = 0; fi < 4; ++fi) {
        const int r = wm * 64 + fi * 16 + lr;
        af[fi] = *(const short8*)(As + r * 128 + (((kk * 4 + lk) ^ (r & 7)) << 4));
      }
#pragma unroll
      for (int fj = 0; fj < 4; ++fj) {
        const int r = wn * 64 + fj * 16 + lr;
        bfr[fj] = *(const short8*)(Bs + r * 128 + (((kk * 4 + lk) ^ (r & 7)) << 4));
      }
      __builtin_amdgcn_s_setprio(1);
#pragma unroll
      for (int fi = 0; fi < 4; ++fi)
#pragma unroll
        for (int fj = 0; fj < 4; ++fj)
          acc[fi][fj] = __builtin_amdgcn_mfma_f32_16x16x32_bf16(
              af[fi], bfr[fj], acc[fi][fj], 0, 0, 0);
      __builtin_amdgcn_s_setprio(0);
    }
    __builtin_amdgcn_s_barrier();      // all waves consumed tile t
    if (t < 19) {
      stage(t + 1);                    // refill the single slot
      VMC(0);                          // drain own loads (co-resident block
      __builtin_amdgcn_s_barrier();    //  computes during this wait)
    }
  }

  // epilogue: dout = acc + Cb + Db
#pragma unroll
  for (int fj = 0; fj < 4; ++fj) {
    const int col = n0 + wn * 64 + fj * 16 + lr;
    const float cb = Cb[col] + Db[col];
#pragma unroll
    for (int fi = 0; fi < 4; ++fi) {
      const int rowb = m0 + wm * 64 + fi * 16 + lk * 4;
#pragma unroll
      for (int j = 0; j < 4; ++j)
        dout[(size_t)(rowb + j) * DIM + col] = acc[fi][fj][j] + cb;
    }
  }
}

extern "C" void kernel_launch(void* const* d_in, const int* in_sizes, int n_in,
                              void* d_out, int out_size, void* d_ws, size_t ws_size,
                              hipStream_t stream) {
  const float* x  = (const float*)d_in[0];
  const float* A  = (const float*)d_in[1];
  const float* Bw = (const float*)d_in[2];
  const float* Bb = (const float*)d_in[3];
  const float* Cw = (const float*)d_in[4];
  const float* Cb = (const float*)d_in[5];
  const float* Dw = (const float*)d_in[6];
  const float* Db = (const float*)d_in[7];
  float* dout = (float*)d_out;

  char* ws = (char*)d_ws;
  unsigned short* xb   = (unsigned short*)(ws);              // 33,554,432 B
  unsigned short* bwb  = (unsigned short*)(ws + 33554432);   //    524,288 B
  unsigned short* wob  = (unsigned short*)(ws + 34078720);   //  2,621,440 B
  unsigned short* G    = (unsigned short*)(ws + 36700160);   //  8,388,608 B
  unsigned short* stb  = (unsigned short*)(ws + 53477376);   //  8,388,608 B -> 61,865,984

  // 1) Bw -> bf16 (tiny)
  convert_bw<<<256, 256, 0, stream>>>(Bw, bwb);
  // 2) fused: G(bf16) = (x @ Bw^T)*C2 + bias ; xb = bf16(x)
  gemm_GX<<<512, 256, 0, stream>>>(x, bwb, Bb, A, G, xb);
  // 3) wob convert head + chunked recurrent scan -> states (bf16)
  scan_kernel<<<BATCH * 64, 256, 0, stream>>>(G, A, Cw, Dw, wob, stb);
  // 4) dout = [states|x] @ [Cw|Dw]^T + Cb + Db  [2-resident single-buffer]
  gemm_out<<<512, 512, 0, stream>>>(stb, xb, wob, Cb, Db, dout);
}